// Round 1
// baseline (3631.514 us; speedup 1.0000x reference)
//
#include <hip/hip_runtime.h>
#include <math.h>

#define NN 100000
#define EE 3200000
#define INC 500
#define HIDN 256
#define OC 64
#define KHOP 10

typedef __attribute__((ext_vector_type(4))) float f4;
typedef __attribute__((ext_vector_type(4))) unsigned short us4;
typedef __attribute__((ext_vector_type(8))) unsigned short us8;

__device__ __forceinline__ float bf2f(unsigned short u) {
    return __uint_as_float(((unsigned int)u) << 16);
}
__device__ __forceinline__ unsigned short f2bf(float f) {
    unsigned int i = __float_as_uint(f);
    i += 0x7fffu + ((i >> 16) & 1u);   // round-to-nearest-even
    return (unsigned short)(i >> 16);
}

// ---------------- GEMM1: h = relu(feat @ W1^T + b1), bf16 out ----------------
// tile: 64 rows x 256 cols (all of HID), KC=16, 256 threads, 8x8 microtile.
__global__ __launch_bounds__(256) void gemm1_k(
    const float* __restrict__ feat, const float* __restrict__ W1,
    const float* __restrict__ b1, unsigned short* __restrict__ h)
{
    __shared__ float sA[16][64];    // k-major A tile
    __shared__ float sB[16][256];   // k-major B tile
    const int t  = threadIdx.x;
    const int m0 = blockIdx.x * 64;
    const int tx = t & 31;          // 32 col-threads -> cols tx*4 and 128+tx*4
    const int ty = t >> 5;          // 8 row-threads  -> rows ty*8..+7
    float acc[8][8];
#pragma unroll
    for (int i = 0; i < 8; ++i)
#pragma unroll
        for (int j = 0; j < 8; ++j) acc[i][j] = 0.f;

    const int sm  = t >> 2;         // 0..63
    const int skq = (t & 3) * 4;    // 0,4,8,12

    for (int k0 = 0; k0 < INC; k0 += 16) {
        // stage A: 64x16, one float4 per thread, coalesced (4 lanes = 64B/row)
        {
            int m = m0 + sm;
            f4 v = {0.f, 0.f, 0.f, 0.f};
            if (m < NN) {
                if (k0 + skq + 3 < INC) {
                    v = *reinterpret_cast<const f4*>(&feat[(size_t)m * INC + k0 + skq]);
                } else {
#pragma unroll
                    for (int i = 0; i < 4; ++i) {
                        int k = k0 + skq + i;
                        if (k < INC) v[i] = feat[(size_t)m * INC + k];
                    }
                }
            }
#pragma unroll
            for (int i = 0; i < 4; ++i) sA[skq + i][sm] = v[i];
        }
        // stage B: 256x16 in 4 passes, same pattern
#pragma unroll
        for (int p = 0; p < 4; ++p) {
            int j = sm + p * 64;
            f4 v = {0.f, 0.f, 0.f, 0.f};
            if (k0 + skq + 3 < INC) {
                v = *reinterpret_cast<const f4*>(&W1[(size_t)j * INC + k0 + skq]);
            } else {
#pragma unroll
                for (int i = 0; i < 4; ++i) {
                    int k = k0 + skq + i;
                    if (k < INC) v[i] = W1[(size_t)j * INC + k];
                }
            }
#pragma unroll
            for (int i = 0; i < 4; ++i) sB[skq + i][j] = v[i];
        }
        __syncthreads();
#pragma unroll
        for (int k = 0; k < 16; ++k) {
            f4 a0 = *reinterpret_cast<const f4*>(&sA[k][ty * 8]);
            f4 a1 = *reinterpret_cast<const f4*>(&sA[k][ty * 8 + 4]);
            f4 c0 = *reinterpret_cast<const f4*>(&sB[k][tx * 4]);
            f4 c1 = *reinterpret_cast<const f4*>(&sB[k][128 + tx * 4]);
            float a[8] = {a0[0], a0[1], a0[2], a0[3], a1[0], a1[1], a1[2], a1[3]};
            float b[8] = {c0[0], c0[1], c0[2], c0[3], c1[0], c1[1], c1[2], c1[3]};
#pragma unroll
            for (int i = 0; i < 8; ++i)
#pragma unroll
                for (int j = 0; j < 8; ++j) acc[i][j] += a[i] * b[j];
        }
        __syncthreads();
    }
    // epilogue: relu(+bias) -> bf16
#pragma unroll
    for (int i = 0; i < 8; ++i) {
        int m = m0 + ty * 8 + i;
        if (m >= NN) continue;
        us4 o0, o1;
#pragma unroll
        for (int j = 0; j < 4; ++j) {
            float v0 = acc[i][j] + b1[tx * 4 + j];
            o0[j] = f2bf(v0 > 0.f ? v0 : 0.f);
            float v1 = acc[i][j + 4] + b1[128 + tx * 4 + j];
            o1[j] = f2bf(v1 > 0.f ? v1 : 0.f);
        }
        *reinterpret_cast<us4*>(&h[(size_t)m * HIDN + tx * 4]) = o0;
        *reinterpret_cast<us4*>(&h[(size_t)m * HIDN + 128 + tx * 4]) = o1;
    }
}

// -------- GEMM2 + combine(k=0): x0 = h @ W2^T + b2; out = sig(x0.pw+pb)*x0 ----
// tile: 64 rows x 64 cols (all of OC), KC=32, 256 threads, 4x4 microtile.
__global__ __launch_bounds__(256) void gemm2_k(
    const unsigned short* __restrict__ h, const float* __restrict__ W2,
    const float* __restrict__ b2, const float* __restrict__ pw,
    const float* __restrict__ pbp, float* __restrict__ out,
    unsigned short* __restrict__ xb)
{
    __shared__ unsigned short sA[32][64];
    __shared__ float sB[32][64];
    __shared__ float sX[64][65];
    const int t  = threadIdx.x;
    const int m0 = blockIdx.x * 64;
    const int tx = t & 15;
    const int ty = t >> 4;
    float acc[4][4];
#pragma unroll
    for (int i = 0; i < 4; ++i)
#pragma unroll
        for (int j = 0; j < 4; ++j) acc[i][j] = 0.f;

    const int am  = t >> 2;         // 0..63
    const int akq = (t & 3) * 8;    // 0,8,16,24

    for (int k0 = 0; k0 < HIDN; k0 += 32) {
        {
            int m = m0 + am;
            us8 v;
#pragma unroll
            for (int i = 0; i < 8; ++i) v[i] = 0;
            if (m < NN)
                v = *reinterpret_cast<const us8*>(&h[(size_t)m * HIDN + k0 + akq]);
#pragma unroll
            for (int i = 0; i < 8; ++i) sA[akq + i][am] = v[i];
        }
#pragma unroll
        for (int p = 0; p < 2; ++p) {
            int fid = t + p * 256;
            int c   = fid >> 3;        // 0..63
            int kq  = (fid & 7) * 4;   // 0..28
            f4 v = *reinterpret_cast<const f4*>(&W2[(size_t)c * HIDN + k0 + kq]);
#pragma unroll
            for (int i = 0; i < 4; ++i) sB[kq + i][c] = v[i];
        }
        __syncthreads();
#pragma unroll
        for (int k = 0; k < 32; ++k) {
            us4 av = *reinterpret_cast<const us4*>(&sA[k][ty * 4]);
            f4  bv = *reinterpret_cast<const f4*>(&sB[k][tx * 4]);
            float a[4] = {bf2f(av[0]), bf2f(av[1]), bf2f(av[2]), bf2f(av[3])};
#pragma unroll
            for (int i = 0; i < 4; ++i)
#pragma unroll
                for (int j = 0; j < 4; ++j) acc[i][j] += a[i] * bv[j];
        }
        __syncthreads();
    }
#pragma unroll
    for (int i = 0; i < 4; ++i)
#pragma unroll
        for (int j = 0; j < 4; ++j)
            sX[ty * 4 + i][tx * 4 + j] = acc[i][j] + b2[tx * 4 + j];
    __syncthreads();
    // sigmoid-attention term for k=0 (initializes out), plus bf16 x0 for prop
    const int row  = t >> 2;
    const int part = t & 3;
    float v = 0.f;
#pragma unroll
    for (int i = 0; i < 16; ++i) {
        int c = part * 16 + i;
        v += sX[row][c] * pw[c];
    }
    v += __shfl_xor(v, 1);
    v += __shfl_xor(v, 2);
    float s = 1.f / (1.f + expf(-(v + pbp[0])));
    int m = m0 + row;
    if (m < NN) {
#pragma unroll
        for (int i = 0; i < 16; ++i) {
            int c = part * 16 + i;
            float val = sX[row][c];
            out[(size_t)m * OC + c] = s * val;
            xb[(size_t)m * OC + c]  = f2bf(val);
        }
    }
}

// ---------------- graph build ----------------
__global__ void deg_k(const int* __restrict__ ei, int* __restrict__ cnt) {
    int e = blockIdx.x * blockDim.x + threadIdx.x;
    if (e >= EE) return;
    int r = ei[e], c = ei[EE + e];
    if (r != c) atomicAdd(&cnt[c], 1);
}

__global__ __launch_bounds__(256) void scan1_k(const int* __restrict__ cnt,
                                               int* __restrict__ tmp,
                                               int* __restrict__ bsum) {
    __shared__ int sd[256];
    int t = threadIdx.x;
    int i = blockIdx.x * 256 + t;
    int v = (i < NN) ? cnt[i] : 0;
    int x = v;
    sd[t] = x;
    __syncthreads();
    for (int off = 1; off < 256; off <<= 1) {
        int y = (t >= off) ? sd[t - off] : 0;
        __syncthreads();
        x += y;
        sd[t] = x;
        __syncthreads();
    }
    if (i < NN) tmp[i] = x;
    if (t == 255) bsum[blockIdx.x] = x;
}

__global__ __launch_bounds__(512) void scan2_k(const int* __restrict__ bsum,
                                               int* __restrict__ boff, int nb) {
    __shared__ int sd[512];
    int t = threadIdx.x;
    int v = (t < nb) ? bsum[t] : 0;
    int x = v;
    sd[t] = x;
    __syncthreads();
    for (int off = 1; off < 512; off <<= 1) {
        int y = (t >= off) ? sd[t - off] : 0;
        __syncthreads();
        x += y;
        sd[t] = x;
        __syncthreads();
    }
    boff[t] = x - v;  // exclusive
}

__global__ __launch_bounds__(256) void scan3_k(const int* __restrict__ cnt,
                                               const int* __restrict__ tmp,
                                               const int* __restrict__ boff,
                                               int* __restrict__ rowptr) {
    int i = blockIdx.x * 256 + threadIdx.x;
    if (i < NN) {
        rowptr[i] = boff[blockIdx.x] + tmp[i] - cnt[i];
        if (i == NN - 1) rowptr[NN] = boff[blockIdx.x] + tmp[i];
    }
}

__global__ void dinv_k(const int* __restrict__ cnt, float* __restrict__ dinv) {
    int i = blockIdx.x * blockDim.x + threadIdx.x;
    if (i < NN) dinv[i] = rsqrtf((float)cnt[i] + 1.0f);  // deg includes self loop
}

__global__ void fill_k(const int* __restrict__ ei, const int* __restrict__ rowptr,
                       int* __restrict__ fpos, const float* __restrict__ dinv,
                       int* __restrict__ csrc, float* __restrict__ cnrm) {
    int e = blockIdx.x * blockDim.x + threadIdx.x;
    if (e >= EE) return;
    int r = ei[e], c = ei[EE + e];
    if (r != c) {
        int p = rowptr[c] + atomicAdd(&fpos[c], 1);
        csrc[p] = r;
        cnrm[p] = dinv[r] * dinv[c];
    }
}

// ---------------- propagation hop (pull-mode) + attention accumulate ----------
__global__ __launch_bounds__(256) void prop_k(
    const unsigned short* __restrict__ xin, unsigned short* __restrict__ xout,
    const int* __restrict__ rowptr, const int* __restrict__ csrc,
    const float* __restrict__ cnrm, const float* __restrict__ dinv,
    const float* __restrict__ pw, const float* __restrict__ pbp,
    float* __restrict__ out)
{
    int wid  = (int)(((size_t)blockIdx.x * blockDim.x + threadIdx.x) >> 6);
    int lane = threadIdx.x & 63;
    if (wid >= NN) return;
    float di  = dinv[wid];
    float acc = di * di * bf2f(xin[(size_t)wid * OC + lane]);  // self loop
    int p0 = rowptr[wid], p1 = rowptr[wid + 1];
    for (int p = p0; p < p1; ++p) {
        int   r = csrc[p];
        float w = cnrm[p];
        acc += w * bf2f(xin[(size_t)r * OC + lane]);
    }
    xout[(size_t)wid * OC + lane] = f2bf(acc);
    float v = acc * pw[lane];
#pragma unroll
    for (int off = 32; off > 0; off >>= 1) v += __shfl_xor(v, off);
    float s = 1.f / (1.f + expf(-(v + pbp[0])));
    out[(size_t)wid * OC + lane] += s * acc;
}

// ---------------- host launcher ----------------
extern "C" void kernel_launch(void* const* d_in, const int* in_sizes, int n_in,
                              void* d_out, int out_size, void* d_ws, size_t ws_size,
                              hipStream_t stream)
{
    (void)in_sizes; (void)n_in; (void)out_size; (void)ws_size;
    const float* feat = (const float*)d_in[0];
    const int*   ei   = (const int*)d_in[1];
    const float* W1   = (const float*)d_in[2];
    const float* b1   = (const float*)d_in[3];
    const float* W2   = (const float*)d_in[4];
    const float* b2   = (const float*)d_in[5];
    const float* pw   = (const float*)d_in[6];
    const float* pbp  = (const float*)d_in[7];
    float* out = (float*)d_out;

    char* w = (char*)d_ws;
    auto carve = [&](size_t bytes) {
        char* p = w;
        w += (bytes + 255) & ~(size_t)255;
        return p;
    };
    unsigned short* h    = (unsigned short*)carve((size_t)NN * HIDN * 2);
    unsigned short* xb0  = (unsigned short*)carve((size_t)NN * OC * 2);
    unsigned short* xb1  = (unsigned short*)carve((size_t)NN * OC * 2);
    int*   csrc   = (int*)carve((size_t)EE * 4);
    float* cnrm   = (float*)carve((size_t)EE * 4);
    int*   cnt    = (int*)carve((size_t)NN * 4);
    int*   tmp    = (int*)carve((size_t)NN * 4);
    int*   bsum   = (int*)carve(4096);
    int*   boff   = (int*)carve(4096);
    int*   rowptr = (int*)carve((size_t)(NN + 1) * 4);
    int*   fpos   = (int*)carve((size_t)NN * 4);
    float* dinv   = (float*)carve((size_t)NN * 4);

    hipMemsetAsync(cnt, 0, (size_t)NN * 4, stream);
    hipMemsetAsync(fpos, 0, (size_t)NN * 4, stream);

    gemm1_k<<<1563, 256, 0, stream>>>(feat, W1, b1, h);
    deg_k<<<12500, 256, 0, stream>>>(ei, cnt);
    scan1_k<<<391, 256, 0, stream>>>(cnt, tmp, bsum);
    scan2_k<<<1, 512, 0, stream>>>(bsum, boff, 391);
    scan3_k<<<391, 256, 0, stream>>>(cnt, tmp, boff, rowptr);
    dinv_k<<<391, 256, 0, stream>>>(cnt, dinv);
    fill_k<<<12500, 256, 0, stream>>>(ei, rowptr, fpos, dinv, csrc, cnrm);
    gemm2_k<<<1563, 256, 0, stream>>>(h, W2, b2, pw, pbp, out, xb0);

    unsigned short* xi = xb0;
    unsigned short* xo = xb1;
    for (int k = 0; k < KHOP; ++k) {
        prop_k<<<25000, 256, 0, stream>>>(xi, xo, rowptr, csrc, cnrm, dinv, pw, pbp, out);
        unsigned short* t2 = xi; xi = xo; xo = t2;
    }
}

// Round 2
// 1776.621 us; speedup vs baseline: 2.0441x; 2.0441x over previous
//
#include <hip/hip_runtime.h>
#include <math.h>

#define NN 100000
#define EE 3200000
#define INC 500
#define HIDN 256
#define OC 64
#define KHOP 10

typedef __attribute__((ext_vector_type(4))) float f4;
typedef __attribute__((ext_vector_type(4))) unsigned short us4;
typedef __attribute__((ext_vector_type(8))) unsigned short us8;

__device__ __forceinline__ float bf2f(unsigned short u) {
    return __uint_as_float(((unsigned int)u) << 16);
}
__device__ __forceinline__ unsigned short f2bf(float f) {
    unsigned int i = __float_as_uint(f);
    i += 0x7fffu + ((i >> 16) & 1u);   // round-to-nearest-even
    return (unsigned short)(i >> 16);
}

// ---------------- GEMM1: h = relu(feat @ W1^T + b1), bf16 out ----------------
// tile: 64 rows x 256 cols (all of HID), KC=16, 256 threads, 8x8 microtile.
__global__ __launch_bounds__(256) void gemm1_k(
    const float* __restrict__ feat, const float* __restrict__ W1,
    const float* __restrict__ b1, unsigned short* __restrict__ h)
{
    __shared__ float sA[16][64];    // k-major A tile
    __shared__ float sB[16][256];   // k-major B tile
    const int t  = threadIdx.x;
    const int m0 = blockIdx.x * 64;
    const int tx = t & 31;          // 32 col-threads -> cols tx*4 and 128+tx*4
    const int ty = t >> 5;          // 8 row-threads  -> rows ty*8..+7
    float acc[8][8];
#pragma unroll
    for (int i = 0; i < 8; ++i)
#pragma unroll
        for (int j = 0; j < 8; ++j) acc[i][j] = 0.f;

    const int sm  = t >> 2;         // 0..63
    const int skq = (t & 3) * 4;    // 0,4,8,12

    for (int k0 = 0; k0 < INC; k0 += 16) {
        // stage A: 64x16, one float4 per thread, coalesced (4 lanes = 64B/row)
        {
            int m = m0 + sm;
            f4 v = {0.f, 0.f, 0.f, 0.f};
            if (m < NN) {
                if (k0 + skq + 3 < INC) {
                    v = *reinterpret_cast<const f4*>(&feat[(size_t)m * INC + k0 + skq]);
                } else {
#pragma unroll
                    for (int i = 0; i < 4; ++i) {
                        int k = k0 + skq + i;
                        if (k < INC) v[i] = feat[(size_t)m * INC + k];
                    }
                }
            }
#pragma unroll
            for (int i = 0; i < 4; ++i) sA[skq + i][sm] = v[i];
        }
        // stage B: 256x16 in 4 passes, same pattern
#pragma unroll
        for (int p = 0; p < 4; ++p) {
            int j = sm + p * 64;
            f4 v = {0.f, 0.f, 0.f, 0.f};
            if (k0 + skq + 3 < INC) {
                v = *reinterpret_cast<const f4*>(&W1[(size_t)j * INC + k0 + skq]);
            } else {
#pragma unroll
                for (int i = 0; i < 4; ++i) {
                    int k = k0 + skq + i;
                    if (k < INC) v[i] = W1[(size_t)j * INC + k];
                }
            }
#pragma unroll
            for (int i = 0; i < 4; ++i) sB[skq + i][j] = v[i];
        }
        __syncthreads();
#pragma unroll
        for (int k = 0; k < 16; ++k) {
            f4 a0 = *reinterpret_cast<const f4*>(&sA[k][ty * 8]);
            f4 a1 = *reinterpret_cast<const f4*>(&sA[k][ty * 8 + 4]);
            f4 c0 = *reinterpret_cast<const f4*>(&sB[k][tx * 4]);
            f4 c1 = *reinterpret_cast<const f4*>(&sB[k][128 + tx * 4]);
            float a[8] = {a0[0], a0[1], a0[2], a0[3], a1[0], a1[1], a1[2], a1[3]};
            float b[8] = {c0[0], c0[1], c0[2], c0[3], c1[0], c1[1], c1[2], c1[3]};
#pragma unroll
            for (int i = 0; i < 8; ++i)
#pragma unroll
                for (int j = 0; j < 8; ++j) acc[i][j] += a[i] * b[j];
        }
        __syncthreads();
    }
    // epilogue: relu(+bias) -> bf16
#pragma unroll
    for (int i = 0; i < 8; ++i) {
        int m = m0 + ty * 8 + i;
        if (m >= NN) continue;
        us4 o0, o1;
#pragma unroll
        for (int j = 0; j < 4; ++j) {
            float v0 = acc[i][j] + b1[tx * 4 + j];
            o0[j] = f2bf(v0 > 0.f ? v0 : 0.f);
            float v1 = acc[i][j + 4] + b1[128 + tx * 4 + j];
            o1[j] = f2bf(v1 > 0.f ? v1 : 0.f);
        }
        *reinterpret_cast<us4*>(&h[(size_t)m * HIDN + tx * 4]) = o0;
        *reinterpret_cast<us4*>(&h[(size_t)m * HIDN + 128 + tx * 4]) = o1;
    }
}

// -------- GEMM2 + combine(k=0): x0 = h @ W2^T + b2; out = sig(x0.pw+pb)*x0 ----
// tile: 64 rows x 64 cols (all of OC), KC=32, 256 threads, 4x4 microtile.
__global__ __launch_bounds__(256) void gemm2_k(
    const unsigned short* __restrict__ h, const float* __restrict__ W2,
    const float* __restrict__ b2, const float* __restrict__ pw,
    const float* __restrict__ pbp, float* __restrict__ out,
    unsigned short* __restrict__ xb)
{
    __shared__ unsigned short sA[32][64];
    __shared__ float sB[32][64];
    __shared__ float sX[64][65];
    const int t  = threadIdx.x;
    const int m0 = blockIdx.x * 64;
    const int tx = t & 15;
    const int ty = t >> 4;
    float acc[4][4];
#pragma unroll
    for (int i = 0; i < 4; ++i)
#pragma unroll
        for (int j = 0; j < 4; ++j) acc[i][j] = 0.f;

    const int am  = t >> 2;         // 0..63
    const int akq = (t & 3) * 8;    // 0,8,16,24

    for (int k0 = 0; k0 < HIDN; k0 += 32) {
        {
            int m = m0 + am;
            us8 v;
#pragma unroll
            for (int i = 0; i < 8; ++i) v[i] = 0;
            if (m < NN)
                v = *reinterpret_cast<const us8*>(&h[(size_t)m * HIDN + k0 + akq]);
#pragma unroll
            for (int i = 0; i < 8; ++i) sA[akq + i][am] = v[i];
        }
#pragma unroll
        for (int p = 0; p < 2; ++p) {
            int fid = t + p * 256;
            int c   = fid >> 3;        // 0..63
            int kq  = (fid & 7) * 4;   // 0..28
            f4 v = *reinterpret_cast<const f4*>(&W2[(size_t)c * HIDN + k0 + kq]);
#pragma unroll
            for (int i = 0; i < 4; ++i) sB[kq + i][c] = v[i];
        }
        __syncthreads();
#pragma unroll
        for (int k = 0; k < 32; ++k) {
            us4 av = *reinterpret_cast<const us4*>(&sA[k][ty * 4]);
            f4  bv = *reinterpret_cast<const f4*>(&sB[k][tx * 4]);
            float a[4] = {bf2f(av[0]), bf2f(av[1]), bf2f(av[2]), bf2f(av[3])};
#pragma unroll
            for (int i = 0; i < 4; ++i)
#pragma unroll
                for (int j = 0; j < 4; ++j) acc[i][j] += a[i] * bv[j];
        }
        __syncthreads();
    }
#pragma unroll
    for (int i = 0; i < 4; ++i)
#pragma unroll
        for (int j = 0; j < 4; ++j)
            sX[ty * 4 + i][tx * 4 + j] = acc[i][j] + b2[tx * 4 + j];
    __syncthreads();
    // sigmoid-attention term for k=0 (initializes out), plus bf16 x0 for prop
    const int row  = t >> 2;
    const int part = t & 3;
    float v = 0.f;
#pragma unroll
    for (int i = 0; i < 16; ++i) {
        int c = part * 16 + i;
        v += sX[row][c] * pw[c];
    }
    v += __shfl_xor(v, 1);
    v += __shfl_xor(v, 2);
    float s = 1.f / (1.f + expf(-(v + pbp[0])));
    int m = m0 + row;
    if (m < NN) {
#pragma unroll
        for (int i = 0; i < 16; ++i) {
            int c = part * 16 + i;
            float val = sX[row][c];
            out[(size_t)m * OC + c] = s * val;
            xb[(size_t)m * OC + c]  = f2bf(val);
        }
    }
}

// ---------------- graph build ----------------
__global__ void deg_k(const int* __restrict__ ei, int* __restrict__ cnt) {
    int e = blockIdx.x * blockDim.x + threadIdx.x;
    if (e >= EE) return;
    int r = ei[e], c = ei[EE + e];
    if (r != c) atomicAdd(&cnt[c], 1);
}

__global__ __launch_bounds__(256) void scan1_k(const int* __restrict__ cnt,
                                               int* __restrict__ tmp,
                                               int* __restrict__ bsum) {
    __shared__ int sd[256];
    int t = threadIdx.x;
    int i = blockIdx.x * 256 + t;
    int v = (i < NN) ? cnt[i] : 0;
    int x = v;
    sd[t] = x;
    __syncthreads();
    for (int off = 1; off < 256; off <<= 1) {
        int y = (t >= off) ? sd[t - off] : 0;
        __syncthreads();
        x += y;
        sd[t] = x;
        __syncthreads();
    }
    if (i < NN) tmp[i] = x;
    if (t == 255) bsum[blockIdx.x] = x;
}

__global__ __launch_bounds__(512) void scan2_k(const int* __restrict__ bsum,
                                               int* __restrict__ boff, int nb) {
    __shared__ int sd[512];
    int t = threadIdx.x;
    int v = (t < nb) ? bsum[t] : 0;
    int x = v;
    sd[t] = x;
    __syncthreads();
    for (int off = 1; off < 512; off <<= 1) {
        int y = (t >= off) ? sd[t - off] : 0;
        __syncthreads();
        x += y;
        sd[t] = x;
        __syncthreads();
    }
    boff[t] = x - v;  // exclusive
}

__global__ __launch_bounds__(256) void scan3_k(const int* __restrict__ cnt,
                                               const int* __restrict__ tmp,
                                               const int* __restrict__ boff,
                                               int* __restrict__ rowptr) {
    int i = blockIdx.x * 256 + threadIdx.x;
    if (i < NN) {
        rowptr[i] = boff[blockIdx.x] + tmp[i] - cnt[i];
        if (i == NN - 1) rowptr[NN] = boff[blockIdx.x] + tmp[i];
    }
}

__global__ void dinv_k(const int* __restrict__ cnt, float* __restrict__ dinv) {
    int i = blockIdx.x * blockDim.x + threadIdx.x;
    if (i < NN) dinv[i] = rsqrtf((float)cnt[i] + 1.0f);  // deg includes self loop
}

__global__ void fill_k(const int* __restrict__ ei, const int* __restrict__ rowptr,
                       int* __restrict__ fpos, const float* __restrict__ dinv,
                       int* __restrict__ csrc, float* __restrict__ cnrm) {
    int e = blockIdx.x * blockDim.x + threadIdx.x;
    if (e >= EE) return;
    int r = ei[e], c = ei[EE + e];
    if (r != c) {
        int p = rowptr[c] + atomicAdd(&fpos[c], 1);
        csrc[p] = r;
        cnrm[p] = dinv[r] * dinv[c];
    }
}

// ---------------- propagation hop (pull-mode) + attention accumulate ----------
// One wave per node. Lanes cooperatively load up to 64 (src,norm) pairs with
// two coalesced loads, then shfl-broadcast so 4 independent gathers are in
// flight per step (breaks the serial csrc->xin dependent-load chain).
__global__ __launch_bounds__(256) void prop_k(
    const unsigned short* __restrict__ xin, unsigned short* __restrict__ xout,
    const int* __restrict__ rowptr, const int* __restrict__ csrc,
    const float* __restrict__ cnrm, const float* __restrict__ dinv,
    const float* __restrict__ pw, const float* __restrict__ pbp,
    float* __restrict__ out)
{
    int wid  = blockIdx.x * 4 + (threadIdx.x >> 6);
    int lane = threadIdx.x & 63;
    if (wid >= NN) return;
    float di = dinv[wid];
    float a0 = di * di * bf2f(xin[(size_t)wid * OC + lane]);  // self loop
    float a1 = 0.f, a2 = 0.f, a3 = 0.f;
    int p0 = rowptr[wid], p1 = rowptr[wid + 1];
    for (int base = p0; base < p1; base += 64) {
        int n = p1 - base;
        if (n > 64) n = 64;
        int   sv = 0;
        float wv = 0.f;
        if (lane < n) {
            sv = csrc[base + lane];
            wv = cnrm[base + lane];
        }
        int j = 0;
        for (; j + 4 <= n; j += 4) {
            int   r0 = __shfl(sv, j    );
            int   r1 = __shfl(sv, j + 1);
            int   r2 = __shfl(sv, j + 2);
            int   r3 = __shfl(sv, j + 3);
            float w0 = __shfl(wv, j    );
            float w1 = __shfl(wv, j + 1);
            float w2 = __shfl(wv, j + 2);
            float w3 = __shfl(wv, j + 3);
            float x0 = bf2f(xin[(size_t)r0 * OC + lane]);
            float x1 = bf2f(xin[(size_t)r1 * OC + lane]);
            float x2 = bf2f(xin[(size_t)r2 * OC + lane]);
            float x3 = bf2f(xin[(size_t)r3 * OC + lane]);
            a0 += w0 * x0;
            a1 += w1 * x1;
            a2 += w2 * x2;
            a3 += w3 * x3;
        }
        for (; j < n; ++j) {
            int   r  = __shfl(sv, j);
            float wj = __shfl(wv, j);
            a0 += wj * bf2f(xin[(size_t)r * OC + lane]);
        }
    }
    float acc = (a0 + a1) + (a2 + a3);
    xout[(size_t)wid * OC + lane] = f2bf(acc);
    float v = acc * pw[lane];
#pragma unroll
    for (int off = 32; off > 0; off >>= 1) v += __shfl_xor(v, off);
    float s = 1.f / (1.f + expf(-(v + pbp[0])));
    out[(size_t)wid * OC + lane] += s * acc;
}

// ---------------- host launcher ----------------
extern "C" void kernel_launch(void* const* d_in, const int* in_sizes, int n_in,
                              void* d_out, int out_size, void* d_ws, size_t ws_size,
                              hipStream_t stream)
{
    (void)in_sizes; (void)n_in; (void)out_size; (void)ws_size;
    const float* feat = (const float*)d_in[0];
    const int*   ei   = (const int*)d_in[1];
    const float* W1   = (const float*)d_in[2];
    const float* b1   = (const float*)d_in[3];
    const float* W2   = (const float*)d_in[4];
    const float* b2   = (const float*)d_in[5];
    const float* pw   = (const float*)d_in[6];
    const float* pbp  = (const float*)d_in[7];
    float* out = (float*)d_out;

    char* w = (char*)d_ws;
    auto carve = [&](size_t bytes) {
        char* p = w;
        w += (bytes + 255) & ~(size_t)255;
        return p;
    };
    unsigned short* h    = (unsigned short*)carve((size_t)NN * HIDN * 2);
    unsigned short* xb0  = (unsigned short*)carve((size_t)NN * OC * 2);
    unsigned short* xb1  = (unsigned short*)carve((size_t)NN * OC * 2);
    int*   csrc   = (int*)carve((size_t)EE * 4);
    float* cnrm   = (float*)carve((size_t)EE * 4);
    int*   cnt    = (int*)carve((size_t)NN * 4);
    int*   tmp    = (int*)carve((size_t)NN * 4);
    int*   bsum   = (int*)carve(4096);
    int*   boff   = (int*)carve(4096);
    int*   rowptr = (int*)carve((size_t)(NN + 1) * 4);
    int*   fpos   = (int*)carve((size_t)NN * 4);
    float* dinv   = (float*)carve((size_t)NN * 4);

    hipMemsetAsync(cnt, 0, (size_t)NN * 4, stream);
    hipMemsetAsync(fpos, 0, (size_t)NN * 4, stream);

    gemm1_k<<<1563, 256, 0, stream>>>(feat, W1, b1, h);
    deg_k<<<12500, 256, 0, stream>>>(ei, cnt);
    scan1_k<<<391, 256, 0, stream>>>(cnt, tmp, bsum);
    scan2_k<<<1, 512, 0, stream>>>(bsum, boff, 391);
    scan3_k<<<391, 256, 0, stream>>>(cnt, tmp, boff, rowptr);
    dinv_k<<<391, 256, 0, stream>>>(cnt, dinv);
    fill_k<<<12500, 256, 0, stream>>>(ei, rowptr, fpos, dinv, csrc, cnrm);
    gemm2_k<<<1563, 256, 0, stream>>>(h, W2, b2, pw, pbp, out, xb0);

    unsigned short* xi = xb0;
    unsigned short* xo = xb1;
    for (int k = 0; k < KHOP; ++k) {
        prop_k<<<25000, 256, 0, stream>>>(xi, xo, rowptr, csrc, cnrm, dinv, pw, pbp, out);
        unsigned short* t2 = xi; xi = xo; xo = t2;
    }
}

// Round 3
// 1597.009 us; speedup vs baseline: 2.2739x; 1.1125x over previous
//
#include <hip/hip_runtime.h>
#include <math.h>

#define NN 100000
#define EE 3200000
#define INC 500
#define HIDN 256
#define OC 64
#define KHOP 10
#define LDA 40   // bf16 elems per LDS row: 32 data + 8 pad (80B rows, breaks bank aliasing)

typedef __attribute__((ext_vector_type(4))) float f4;
typedef __attribute__((ext_vector_type(4))) unsigned short us4;
typedef __attribute__((ext_vector_type(8))) unsigned short us8;
typedef __attribute__((ext_vector_type(8))) short short8;   // MFMA bf16x8 frag
typedef __attribute__((ext_vector_type(4))) float f32x4;    // MFMA acc

__device__ __forceinline__ float bf2f(unsigned short u) {
    return __uint_as_float(((unsigned int)u) << 16);
}
__device__ __forceinline__ unsigned short f2bf(float f) {
    unsigned int i = __float_as_uint(f);
    i += 0x7fffu + ((i >> 16) & 1u);   // round-to-nearest-even
    return (unsigned short)(i >> 16);
}
__device__ __forceinline__ us8 pack8(f4 a, f4 b) {
    us8 r;
    r[0] = f2bf(a[0]); r[1] = f2bf(a[1]); r[2] = f2bf(a[2]); r[3] = f2bf(a[3]);
    r[4] = f2bf(b[0]); r[5] = f2bf(b[1]); r[6] = f2bf(b[2]); r[7] = f2bf(b[3]);
    return r;
}

// ------------- GEMM1 (MFMA): h = relu(feat @ W1^T + b1), bf16 out -----------
// BM=64, BN=256 (full HID), BK=32. 4 waves, wave w owns cols w*64..w*64+63.
// Per wave: 4x4 fragments of 16x16x32 bf16 MFMA, fp32 accum.
__global__ __launch_bounds__(256) void gemm1_k(
    const float* __restrict__ feat, const float* __restrict__ W1,
    const float* __restrict__ b1, unsigned short* __restrict__ h)
{
    __shared__ unsigned short sA[64 * LDA];    // feat tile, k-contig rows
    __shared__ unsigned short sB[256 * LDA];   // W1 rows,   k-contig rows

    const int t    = threadIdx.x;
    const int m0   = blockIdx.x * 64;
    const int wc   = t >> 6;        // wave 0..3 -> col group
    const int lane = t & 63;
    const int lg   = lane >> 4;     // k-group 0..3 (8 k each)
    const int lm   = lane & 15;     // row/col within fragment

    f32x4 acc[4][4];
#pragma unroll
    for (int i = 0; i < 4; ++i)
#pragma unroll
        for (int j = 0; j < 4; ++j) acc[i][j] = (f32x4){0.f, 0.f, 0.f, 0.f};

    const int arow = t >> 2;          // 0..63
    const int akq  = (t & 3) * 8;     // 0,8,16,24

    for (int k0 = 0; k0 < 512; k0 += 32) {
        // stage A: 64 rows x 32 k (8 floats/thread -> 8 bf16, one b128 write)
        {
            int gm = m0 + arow;
            int kk = k0 + akq;
            f4 va = {0.f, 0.f, 0.f, 0.f}, vb = {0.f, 0.f, 0.f, 0.f};
            if (gm < NN) {
                const float* p = &feat[(size_t)gm * INC + kk];
                if (kk     < INC) va = *reinterpret_cast<const f4*>(p);     // INC%4==0
                if (kk + 4 < INC) vb = *reinterpret_cast<const f4*>(p + 4);
            }
            *reinterpret_cast<us8*>(&sA[arow * LDA + akq]) = pack8(va, vb);
        }
        // stage B: 256 rows x 32 k in 2 passes (16 floats/thread/pass)
#pragma unroll
        for (int p = 0; p < 2; ++p) {
            int fid = t + p * 256;
            int row = fid >> 1;
            int kq  = (fid & 1) * 16;
            int kk  = k0 + kq;
            const float* pp = &W1[(size_t)row * INC + kk];
            f4 v0 = {0.f,0.f,0.f,0.f}, v1 = {0.f,0.f,0.f,0.f};
            f4 v2 = {0.f,0.f,0.f,0.f}, v3 = {0.f,0.f,0.f,0.f};
            if (kk      < INC) v0 = *reinterpret_cast<const f4*>(pp);
            if (kk + 4  < INC) v1 = *reinterpret_cast<const f4*>(pp + 4);
            if (kk + 8  < INC) v2 = *reinterpret_cast<const f4*>(pp + 8);
            if (kk + 12 < INC) v3 = *reinterpret_cast<const f4*>(pp + 12);
            *reinterpret_cast<us8*>(&sB[row * LDA + kq])     = pack8(v0, v1);
            *reinterpret_cast<us8*>(&sB[row * LDA + kq + 8]) = pack8(v2, v3);
        }
        __syncthreads();
        short8 aF[4], bF[4];
#pragma unroll
        for (int mi = 0; mi < 4; ++mi)
            aF[mi] = *reinterpret_cast<const short8*>(&sA[(mi * 16 + lm) * LDA + lg * 8]);
#pragma unroll
        for (int ni = 0; ni < 4; ++ni)
            bF[ni] = *reinterpret_cast<const short8*>(&sB[(wc * 64 + ni * 16 + lm) * LDA + lg * 8]);
#pragma unroll
        for (int mi = 0; mi < 4; ++mi)
#pragma unroll
            for (int ni = 0; ni < 4; ++ni)
                acc[mi][ni] = __builtin_amdgcn_mfma_f32_16x16x32_bf16(
                    aF[mi], bF[ni], acc[mi][ni], 0, 0, 0);
        __syncthreads();
    }
    // epilogue: C row = mi*16 + lg*4 + r, col = wc*64 + ni*16 + lm
    float bias[4];
#pragma unroll
    for (int ni = 0; ni < 4; ++ni) bias[ni] = b1[wc * 64 + ni * 16 + lm];
#pragma unroll
    for (int mi = 0; mi < 4; ++mi) {
#pragma unroll
        for (int r = 0; r < 4; ++r) {
            int row = m0 + mi * 16 + lg * 4 + r;
            if (row >= NN) continue;
            size_t base = (size_t)row * HIDN + wc * 64;
#pragma unroll
            for (int ni = 0; ni < 4; ++ni) {
                float v = acc[mi][ni][r] + bias[ni];
                h[base + ni * 16 + lm] = f2bf(v > 0.f ? v : 0.f);
            }
        }
    }
}

// -------- GEMM2: x0 = h @ W2^T + b2 (+ optional k=0 combine term) ------------
__global__ __launch_bounds__(256) void gemm2_k(
    const unsigned short* __restrict__ h, const float* __restrict__ W2,
    const float* __restrict__ b2, const float* __restrict__ pw,
    const float* __restrict__ pbp, float* __restrict__ out,
    unsigned short* __restrict__ xb, int writeOut)
{
    __shared__ unsigned short sA[32][64];
    __shared__ float sB[32][64];
    __shared__ float sX[64][65];
    const int t  = threadIdx.x;
    const int m0 = blockIdx.x * 64;
    const int tx = t & 15;
    const int ty = t >> 4;
    float acc[4][4];
#pragma unroll
    for (int i = 0; i < 4; ++i)
#pragma unroll
        for (int j = 0; j < 4; ++j) acc[i][j] = 0.f;

    const int am  = t >> 2;         // 0..63
    const int akq = (t & 3) * 8;    // 0,8,16,24

    for (int k0 = 0; k0 < HIDN; k0 += 32) {
        {
            int m = m0 + am;
            us8 v;
#pragma unroll
            for (int i = 0; i < 8; ++i) v[i] = 0;
            if (m < NN)
                v = *reinterpret_cast<const us8*>(&h[(size_t)m * HIDN + k0 + akq]);
#pragma unroll
            for (int i = 0; i < 8; ++i) sA[akq + i][am] = v[i];
        }
#pragma unroll
        for (int p = 0; p < 2; ++p) {
            int fid = t + p * 256;
            int c   = fid >> 3;
            int kq  = (fid & 7) * 4;
            f4 v = *reinterpret_cast<const f4*>(&W2[(size_t)c * HIDN + k0 + kq]);
#pragma unroll
            for (int i = 0; i < 4; ++i) sB[kq + i][c] = v[i];
        }
        __syncthreads();
#pragma unroll
        for (int k = 0; k < 32; ++k) {
            us4 av = *reinterpret_cast<const us4*>(&sA[k][ty * 4]);
            f4  bv = *reinterpret_cast<const f4*>(&sB[k][tx * 4]);
            float a[4] = {bf2f(av[0]), bf2f(av[1]), bf2f(av[2]), bf2f(av[3])};
#pragma unroll
            for (int i = 0; i < 4; ++i)
#pragma unroll
                for (int j = 0; j < 4; ++j) acc[i][j] += a[i] * bv[j];
        }
        __syncthreads();
    }
#pragma unroll
    for (int i = 0; i < 4; ++i)
#pragma unroll
        for (int j = 0; j < 4; ++j)
            sX[ty * 4 + i][tx * 4 + j] = acc[i][j] + b2[tx * 4 + j];
    __syncthreads();
    const int row  = t >> 2;
    const int part = t & 3;
    float v = 0.f;
#pragma unroll
    for (int i = 0; i < 16; ++i) {
        int c = part * 16 + i;
        v += sX[row][c] * pw[c];
    }
    v += __shfl_xor(v, 1);
    v += __shfl_xor(v, 2);
    float s = 1.f / (1.f + expf(-(v + pbp[0])));
    int m = m0 + row;
    if (m < NN) {
#pragma unroll
        for (int i = 0; i < 16; ++i) {
            int c = part * 16 + i;
            float val = sX[row][c];
            if (writeOut) out[(size_t)m * OC + c] = s * val;
            xb[(size_t)m * OC + c] = f2bf(val);
        }
    }
}

// ---------------- graph build ----------------
__global__ void deg_k(const int* __restrict__ ei, int* __restrict__ cnt) {
    int e = blockIdx.x * blockDim.x + threadIdx.x;
    if (e >= EE) return;
    int r = ei[e], c = ei[EE + e];
    if (r != c) atomicAdd(&cnt[c], 1);
}

__global__ __launch_bounds__(256) void scan1_k(const int* __restrict__ cnt,
                                               int* __restrict__ tmp,
                                               int* __restrict__ bsum) {
    __shared__ int sd[256];
    int t = threadIdx.x;
    int i = blockIdx.x * 256 + t;
    int v = (i < NN) ? cnt[i] : 0;
    int x = v;
    sd[t] = x;
    __syncthreads();
    for (int off = 1; off < 256; off <<= 1) {
        int y = (t >= off) ? sd[t - off] : 0;
        __syncthreads();
        x += y;
        sd[t] = x;
        __syncthreads();
    }
    if (i < NN) tmp[i] = x;
    if (t == 255) bsum[blockIdx.x] = x;
}

__global__ __launch_bounds__(512) void scan2_k(const int* __restrict__ bsum,
                                               int* __restrict__ boff, int nb) {
    __shared__ int sd[512];
    int t = threadIdx.x;
    int v = (t < nb) ? bsum[t] : 0;
    int x = v;
    sd[t] = x;
    __syncthreads();
    for (int off = 1; off < 512; off <<= 1) {
        int y = (t >= off) ? sd[t - off] : 0;
        __syncthreads();
        x += y;
        sd[t] = x;
        __syncthreads();
    }
    boff[t] = x - v;  // exclusive
}

__global__ __launch_bounds__(256) void scan3_k(const int* __restrict__ cnt,
                                               const int* __restrict__ tmp,
                                               const int* __restrict__ boff,
                                               int* __restrict__ rowptr) {
    int i = blockIdx.x * 256 + threadIdx.x;
    if (i < NN) {
        rowptr[i] = boff[blockIdx.x] + tmp[i] - cnt[i];
        if (i == NN - 1) rowptr[NN] = boff[blockIdx.x] + tmp[i];
    }
}

__global__ void dinv_k(const int* __restrict__ cnt, float* __restrict__ dinv) {
    int i = blockIdx.x * blockDim.x + threadIdx.x;
    if (i < NN) dinv[i] = rsqrtf((float)cnt[i] + 1.0f);  // deg includes self loop
}

// packed edge: .x = src node, .y = bitcast(norm)
__global__ void fill_k(const int* __restrict__ ei, const int* __restrict__ rowptr,
                       int* __restrict__ fpos, const float* __restrict__ dinv,
                       int2* __restrict__ epk) {
    int e = blockIdx.x * blockDim.x + threadIdx.x;
    if (e >= EE) return;
    int r = ei[e], c = ei[EE + e];
    if (r != c) {
        int p = rowptr[c] + atomicAdd(&fpos[c], 1);
        epk[p] = make_int2(r, __float_as_int(dinv[r] * dinv[c]));
    }
}

// ---------------- propagation hop (pull-mode) ----------------
// One wave per node; lanes cooperatively load up to 64 packed (src,norm) in one
// coalesced int2 load, shfl-broadcast, keep 4 gathers in flight.
template <int ACCUM>
__global__ __launch_bounds__(256) void prop_k(
    const unsigned short* __restrict__ xin, unsigned short* __restrict__ xout,
    const int* __restrict__ rowptr, const int2* __restrict__ epk,
    const float* __restrict__ dinv, const float* __restrict__ pw,
    const float* __restrict__ pbp, float* __restrict__ out)
{
    int wid  = blockIdx.x * 4 + (threadIdx.x >> 6);
    int lane = threadIdx.x & 63;
    if (wid >= NN) return;
    float di = dinv[wid];
    float a0 = di * di * bf2f(xin[(size_t)wid * OC + lane]);  // self loop
    float a1 = 0.f, a2 = 0.f, a3 = 0.f;
    int p0 = rowptr[wid], p1 = rowptr[wid + 1];
    for (int base = p0; base < p1; base += 64) {
        int n = p1 - base;
        if (n > 64) n = 64;
        int2 e = make_int2(0, 0);
        if (lane < n) e = epk[base + lane];
        int   sv = e.x;
        float wv = __int_as_float(e.y);
        int j = 0;
        for (; j + 4 <= n; j += 4) {
            int   r0 = __shfl(sv, j    );
            int   r1 = __shfl(sv, j + 1);
            int   r2 = __shfl(sv, j + 2);
            int   r3 = __shfl(sv, j + 3);
            float w0 = __shfl(wv, j    );
            float w1 = __shfl(wv, j + 1);
            float w2 = __shfl(wv, j + 2);
            float w3 = __shfl(wv, j + 3);
            float x0 = bf2f(xin[(size_t)r0 * OC + lane]);
            float x1 = bf2f(xin[(size_t)r1 * OC + lane]);
            float x2 = bf2f(xin[(size_t)r2 * OC + lane]);
            float x3 = bf2f(xin[(size_t)r3 * OC + lane]);
            a0 += w0 * x0;
            a1 += w1 * x1;
            a2 += w2 * x2;
            a3 += w3 * x3;
        }
        for (; j < n; ++j) {
            int   r  = __shfl(sv, j);
            float wj = __shfl(wv, j);
            a0 += wj * bf2f(xin[(size_t)r * OC + lane]);
        }
    }
    float acc = (a0 + a1) + (a2 + a3);
    xout[(size_t)wid * OC + lane] = f2bf(acc);
    if (ACCUM) {
        float v = acc * pw[lane];
#pragma unroll
        for (int off = 32; off > 0; off >>= 1) v += __shfl_xor(v, off);
        float s = 1.f / (1.f + expf(-(v + pbp[0])));
        out[(size_t)wid * OC + lane] += s * acc;
    }
}

// ---------------- final sigmoid-attention combine (big-ws path) --------------
__global__ __launch_bounds__(256) void combine_k(
    const unsigned short* __restrict__ xs, const float* __restrict__ pw,
    const float* __restrict__ pbp, float* __restrict__ out)
{
    int wid  = blockIdx.x * 4 + (threadIdx.x >> 6);
    int lane = threadIdx.x & 63;
    if (wid >= NN) return;
    float pwl = pw[lane];
    float pb  = pbp[0];
    float o   = 0.f;
#pragma unroll
    for (int k = 0; k <= KHOP; ++k) {
        float x = bf2f(xs[(size_t)k * NN * OC + (size_t)wid * OC + lane]);
        float v = x * pwl;
#pragma unroll
        for (int off = 32; off > 0; off >>= 1) v += __shfl_xor(v, off);
        float s = 1.f / (1.f + expf(-(v + pb)));
        o += s * x;
    }
    out[(size_t)wid * OC + lane] = o;
}

// ---------------- host launcher ----------------
extern "C" void kernel_launch(void* const* d_in, const int* in_sizes, int n_in,
                              void* d_out, int out_size, void* d_ws, size_t ws_size,
                              hipStream_t stream)
{
    (void)in_sizes; (void)n_in; (void)out_size;
    const float* feat = (const float*)d_in[0];
    const int*   ei   = (const int*)d_in[1];
    const float* W1   = (const float*)d_in[2];
    const float* b1   = (const float*)d_in[3];
    const float* W2   = (const float*)d_in[4];
    const float* b2   = (const float*)d_in[5];
    const float* pw   = (const float*)d_in[6];
    const float* pbp  = (const float*)d_in[7];
    float* out = (float*)d_out;

    char* w = (char*)d_ws;
    size_t used = 0;
    auto carve = [&](size_t bytes) {
        char* p = w + used;
        used += (bytes + 255) & ~(size_t)255;
        return p;
    };
    const size_t XSZ = (size_t)NN * OC * 2;  // one x_k slot (bf16), 256-aligned

    unsigned short* h      = (unsigned short*)carve((size_t)NN * HIDN * 2);
    int2*  epk    = (int2*)carve((size_t)EE * 8);
    int*   cnt    = (int*)carve((size_t)NN * 4);
    int*   tmp    = (int*)carve((size_t)NN * 4);
    int*   bsum   = (int*)carve(4096);
    int*   boff   = (int*)carve(4096);
    int*   rowptr = (int*)carve((size_t)(NN + 1) * 4);
    int*   fpos   = (int*)carve((size_t)NN * 4);
    float* dinv   = (float*)carve((size_t)NN * 4);

    // big path: keep all K+1 hop states, one final combine (no per-hop out RMW)
    bool big = (ws_size - used) >= (size_t)(KHOP + 1) * XSZ;
    unsigned short* xs = (unsigned short*)carve(big ? (KHOP + 1) * XSZ : 2 * XSZ);

    hipMemsetAsync(cnt, 0, (size_t)NN * 4, stream);
    hipMemsetAsync(fpos, 0, (size_t)NN * 4, stream);

    gemm1_k<<<1563, 256, 0, stream>>>(feat, W1, b1, h);
    deg_k<<<12500, 256, 0, stream>>>(ei, cnt);
    scan1_k<<<391, 256, 0, stream>>>(cnt, tmp, bsum);
    scan2_k<<<1, 512, 0, stream>>>(bsum, boff, 391);
    scan3_k<<<391, 256, 0, stream>>>(cnt, tmp, boff, rowptr);
    dinv_k<<<391, 256, 0, stream>>>(cnt, dinv);
    fill_k<<<12500, 256, 0, stream>>>(ei, rowptr, fpos, dinv, epk);
    gemm2_k<<<1563, 256, 0, stream>>>(h, W2, b2, pw, pbp, out,
                                      xs /* x_0 */, big ? 0 : 1);

    if (big) {
        for (int k = 0; k < KHOP; ++k) {
            unsigned short* xi = xs + (size_t)k * NN * OC;
            unsigned short* xo = xs + (size_t)(k + 1) * NN * OC;
            prop_k<0><<<25000, 256, 0, stream>>>(xi, xo, rowptr, epk, dinv,
                                                 pw, pbp, out);
        }
        combine_k<<<25000, 256, 0, stream>>>(xs, pw, pbp, out);
    } else {
        unsigned short* xi = xs;
        unsigned short* xo = xs + NN * OC;
        for (int k = 0; k < KHOP; ++k) {
            prop_k<1><<<25000, 256, 0, stream>>>(xi, xo, rowptr, epk, dinv,
                                                 pw, pbp, out);
            unsigned short* t2 = xi; xi = xo; xo = t2;
        }
    }
}